// Round 1
// baseline (379.496 us; speedup 1.0000x reference)
//
#include <hip/hip_runtime.h>

// Problem constants (from reference)
#define B_    256
#define CIN   48
#define CBOT  8
#define H_    4096
#define SCALE_ 0.35355339059327373f   // 1/sqrt(8)

// One block per batch. 1024 threads; thread t owns h = 4t .. 4t+3 (float4).
// kqv kept entirely in registers; gram reduced via shuffles + tiny LDS.
__global__ __launch_bounds__(1024) void ultimus_kernel(
    const float* __restrict__ x,        // [B, 48, 4096]
    const float* __restrict__ w_down,   // [8, 48]
    const float* __restrict__ w_up,     // [48, 8]
    float* __restrict__ out)            // [B, 48, 4096]
{
    const int b = blockIdx.x;
    const int t = threadIdx.x;

    __shared__ float s_wdT[CIN * CBOT];   // transposed: [c][o], contiguous per c
    __shared__ float s_wu [CIN * CBOT];   // [c][o] as given (row-major [48,8])
    __shared__ float s_red[16 * 36];      // per-wave gram partials
    __shared__ float s_am [CBOT * CBOT];  // softmaxed attention matrix

    // Preload weights (384 elements each)
    if (t < CIN * CBOT) {
        const int c = t >> 3, o = t & 7;
        s_wdT[t] = w_down[o * CIN + c];
        s_wu[t]  = w_up[t];
    }
    __syncthreads();

    const float* xb = x + (size_t)b * (CIN * H_);
    const int h0 = t << 2;

    // ---- Phase 1: kqv[o][0..3] = sum_c w_down[o][c] * x[b][c][h0+0..3] ----
    float kqv[CBOT][4];
    #pragma unroll
    for (int o = 0; o < CBOT; ++o)
        kqv[o][0] = kqv[o][1] = kqv[o][2] = kqv[o][3] = 0.0f;

    #pragma unroll 8
    for (int c = 0; c < CIN; ++c) {
        const float4 xv = *reinterpret_cast<const float4*>(xb + c * H_ + h0);
        #pragma unroll
        for (int o = 0; o < CBOT; ++o) {
            const float w = s_wdT[c * CBOT + o];
            kqv[o][0] += w * xv.x;
            kqv[o][1] += w * xv.y;
            kqv[o][2] += w * xv.z;
            kqv[o][3] += w * xv.w;
        }
    }

    // ---- Phase 2: gram G[i][j] (upper triangle, 36 values), block-reduced ----
    float g[36];
    {
        int idx = 0;
        #pragma unroll
        for (int i = 0; i < CBOT; ++i) {
            #pragma unroll
            for (int j = i; j < CBOT; ++j, ++idx) {
                g[idx] = kqv[i][0] * kqv[j][0] + kqv[i][1] * kqv[j][1]
                       + kqv[i][2] * kqv[j][2] + kqv[i][3] * kqv[j][3];
            }
        }
    }
    // wave-level reduce (64 lanes)
    #pragma unroll
    for (int k = 0; k < 36; ++k) {
        float v = g[k];
        v += __shfl_down(v, 32, 64);
        v += __shfl_down(v, 16, 64);
        v += __shfl_down(v,  8, 64);
        v += __shfl_down(v,  4, 64);
        v += __shfl_down(v,  2, 64);
        v += __shfl_down(v,  1, 64);
        g[k] = v;   // lane 0 holds wave sum
    }
    const int wave = t >> 6;
    const int lane = t & 63;
    if (lane == 0) {
        #pragma unroll
        for (int k = 0; k < 36; ++k) s_red[wave * 36 + k] = g[k];
    }
    __syncthreads();

    // cross-wave reduce: lanes 0..35 of wave 0 (each reads own slot first, then writes it)
    if (t < 36) {
        float v = 0.0f;
        #pragma unroll
        for (int w = 0; w < 16; ++w) v += s_red[w * 36 + t];
        s_red[t] = v;
    }
    __syncthreads();

    // softmax rows: lanes 0..7, row t
    if (t < 8) {
        float row[8];
        #pragma unroll
        for (int j = 0; j < 8; ++j) {
            const int i2 = t < j ? t : j;
            const int j2 = t < j ? j : t;
            const int tri = i2 * 8 - (i2 * (i2 - 1)) / 2 + (j2 - i2);
            row[j] = s_red[tri] * SCALE_;
        }
        float m = row[0];
        #pragma unroll
        for (int j = 1; j < 8; ++j) m = fmaxf(m, row[j]);
        float s = 0.0f;
        #pragma unroll
        for (int j = 0; j < 8; ++j) { row[j] = __expf(row[j] - m); s += row[j]; }
        const float inv = 1.0f / s;
        #pragma unroll
        for (int j = 0; j < 8; ++j) s_am[t * 8 + j] = row[j] * inv;
    }
    __syncthreads();

    // ---- Phase 3: z = am @ kqv (registers), out = w_up @ z ----
    float z[CBOT][4];
    #pragma unroll
    for (int o = 0; o < CBOT; ++o) {
        float a0 = 0.f, a1 = 0.f, a2 = 0.f, a3 = 0.f;
        #pragma unroll
        for (int j = 0; j < CBOT; ++j) {
            const float a = s_am[o * 8 + j];
            a0 += a * kqv[j][0];
            a1 += a * kqv[j][1];
            a2 += a * kqv[j][2];
            a3 += a * kqv[j][3];
        }
        z[o][0] = a0; z[o][1] = a1; z[o][2] = a2; z[o][3] = a3;
    }

    float* ob = out + (size_t)b * (CIN * H_);
    #pragma unroll 8
    for (int c = 0; c < CIN; ++c) {
        float4 r;
        r.x = r.y = r.z = r.w = 0.0f;
        #pragma unroll
        for (int o = 0; o < CBOT; ++o) {
            const float w = s_wu[c * CBOT + o];
            r.x += w * z[o][0];
            r.y += w * z[o][1];
            r.z += w * z[o][2];
            r.w += w * z[o][3];
        }
        *reinterpret_cast<float4*>(ob + c * H_ + h0) = r;
    }
}

extern "C" void kernel_launch(void* const* d_in, const int* in_sizes, int n_in,
                              void* d_out, int out_size, void* d_ws, size_t ws_size,
                              hipStream_t stream) {
    const float* x      = (const float*)d_in[0];
    const float* w_down = (const float*)d_in[1];
    const float* w_up   = (const float*)d_in[2];
    float* out          = (float*)d_out;

    hipLaunchKernelGGL(ultimus_kernel, dim3(B_), dim3(1024), 0, stream,
                       x, w_down, w_up, out);
}